// Round 1
// baseline (318.239 us; speedup 1.0000x reference)
//
#include <hip/hip_runtime.h>
#include <math.h>

// Bit-exact replication of the JAX/numpy reference requires no FMA contraction
// (numpy rounds mul and add separately).
#pragma clang fp contract(off)

#define TPB    1024
#define NBIN   1024     // histogram bins over score in [0,1); == TPB for the scan
#define CAP    3072     // candidate capacity (expected ~1000 + ~192 cut-bin elems)
#define KTOP   1000     // PRE_NMS_TOPK
#define MAXDET 100
#define SCORE_THRESH 0.05f

// One block per class. Phases:
//  1. LDS histogram of scores > 0.05 (1024 value bins)
//  2. suffix-scan -> cut bin (smallest bin with suffix count >= 1000)
//  3. collect candidates (score,~idx) keys >= cut bin into LDS
//  4. exact rank selection: keep key iff #{keys > mine} < 1000  (== lax.top_k set,
//     ties broken by lower index exactly like top_k)
//  5. decode boxes for kept candidates only (bit-exact reference math)
//  6. greedy NMS by iterated 64-bit key max (== argmax with top_k tie order)
__global__ __launch_bounds__(TPB) void retina_post_kernel(
    const float* __restrict__ cls,
    const float* __restrict__ reg,
    const float* __restrict__ anchors,
    float* __restrict__ out,
    int N, int C, float WH)
{
  const int c   = blockIdx.x;
  const int tid = threadIdx.x;
  const float* sc = cls + (size_t)c * N;

  __shared__ unsigned int       shist[NBIN];
  __shared__ unsigned long long ck[CAP];
  __shared__ unsigned long long kept[KTOP];
  __shared__ unsigned long long warr[TPB / 64];
  __shared__ unsigned long long sbest;
  __shared__ unsigned int scount, skeep;
  __shared__ int scut;
  __shared__ float spick[5];

  // ---- phase 1: histogram ----
  for (int b = tid; b < NBIN; b += TPB) shist[b] = 0u;
  if (tid == 0) { scount = 0u; skeep = 0u; scut = 0; }
  __syncthreads();

  const bool vec = ((N & 3) == 0) && ((((size_t)sc) & 15) == 0);
  if (vec) {
    const float4* sc4 = (const float4*)sc;
    const int n4 = N >> 2;
    for (int q = tid; q < n4; q += TPB) {
      float4 v = sc4[q];
      float s;
      s = v.x; if (s > SCORE_THRESH) { int b = (int)(s * 1024.0f); if (b > NBIN - 1) b = NBIN - 1; atomicAdd(&shist[b], 1u); }
      s = v.y; if (s > SCORE_THRESH) { int b = (int)(s * 1024.0f); if (b > NBIN - 1) b = NBIN - 1; atomicAdd(&shist[b], 1u); }
      s = v.z; if (s > SCORE_THRESH) { int b = (int)(s * 1024.0f); if (b > NBIN - 1) b = NBIN - 1; atomicAdd(&shist[b], 1u); }
      s = v.w; if (s > SCORE_THRESH) { int b = (int)(s * 1024.0f); if (b > NBIN - 1) b = NBIN - 1; atomicAdd(&shist[b], 1u); }
    }
  } else {
    for (int i = tid; i < N; i += TPB) {
      float s = sc[i];
      if (s > SCORE_THRESH) { int b = (int)(s * 1024.0f); if (b > NBIN - 1) b = NBIN - 1; atomicAdd(&shist[b], 1u); }
    }
  }
  __syncthreads();

  // ---- phase 2: inclusive suffix scan over NBIN (== TPB) bins ----
  for (int off = 1; off < NBIN; off <<= 1) {
    unsigned int add = (tid + off < NBIN) ? shist[tid + off] : 0u;
    __syncthreads();
    shist[tid] += add;
    __syncthreads();
  }
  {
    unsigned int me  = shist[tid];
    unsigned int nxt = (tid + 1 < NBIN) ? shist[tid + 1] : 0u;
    if (me >= (unsigned)KTOP && nxt < (unsigned)KTOP) scut = tid;
    // if suffix[0] < KTOP no thread fires and scut stays 0 (take everything)
  }
  __syncthreads();
  const int cut = scut;

  // ---- phase 3: collect candidate keys ----
  if (vec) {
    const float4* sc4 = (const float4*)sc;
    const int n4 = N >> 2;
    for (int q = tid; q < n4; q += TPB) {
      float4 v = sc4[q];
      float ss[4] = {v.x, v.y, v.z, v.w};
      #pragma unroll
      for (int j = 0; j < 4; j++) {
        float s = ss[j];
        if (s > SCORE_THRESH) {
          int b = (int)(s * 1024.0f); if (b > NBIN - 1) b = NBIN - 1;
          if (b >= cut) {
            unsigned int p = atomicAdd(&scount, 1u);
            if (p < (unsigned)CAP) {
              unsigned int i = (unsigned int)((q << 2) + j);
              ck[p] = (((unsigned long long)__float_as_uint(s)) << 32) |
                      (unsigned long long)(~i);
            }
          }
        }
      }
    }
  } else {
    for (int i = tid; i < N; i += TPB) {
      float s = sc[i];
      if (s > SCORE_THRESH) {
        int b = (int)(s * 1024.0f); if (b > NBIN - 1) b = NBIN - 1;
        if (b >= cut) {
          unsigned int p = atomicAdd(&scount, 1u);
          if (p < (unsigned)CAP) {
            ck[p] = (((unsigned long long)__float_as_uint(s)) << 32) |
                    (unsigned long long)(~(unsigned int)i);
          }
        }
      }
    }
  }
  __syncthreads();
  int n = (int)scount; if (n > CAP) n = CAP;

  // ---- phase 4: exact rank selection to the top-KTOP set ----
  for (int j = tid; j < n; j += TPB) {
    unsigned long long my = ck[j];
    int r = 0;
    for (int m = 0; m < n; m++) r += (ck[m] > my) ? 1 : 0;
    if (r < KTOP) {
      unsigned int p = atomicAdd(&skeep, 1u);
      kept[p] = my;   // unordered; NMS key-max restores exact order
    }
  }
  __syncthreads();
  const int nk = (int)skeep;   // == min(n, KTOP), ranks are unique

  // ---- phase 5: decode kept boxes (reference-exact math) ----
  bool active = false;
  unsigned long long key = 0ULL;
  float bx1 = 0.f, by1 = 0.f, bx2 = 0.f, by2 = 0.f, barea = 0.f, bscore = 0.f;
  if (tid < nk) {
    key = kept[tid];
    bscore = __uint_as_float((unsigned int)(key >> 32));
    unsigned int idx = ~((unsigned int)(key & 0xFFFFFFFFull));
    float4 a = ((const float4*)anchors)[idx];
    float aw  = a.z - a.x;
    float ah  = a.w - a.y;
    float acx = a.x + 0.5f * aw;
    float acy = a.y + 0.5f * ah;
    float dx = reg[idx]         * 0.1f;
    float dy = reg[N + idx]     * 0.1f;
    float dw = reg[2 * N + idx] * 0.2f;
    float dh = reg[3 * N + idx] * 0.2f;
    float pcx = acx + dx * aw;
    float pcy = acy + dy * ah;
    float pw = (float)exp((double)dw) * aw;   // double exp -> correctly rounded f32
    float ph = (float)exp((double)dh) * ah;
    float x1 = fmaxf(pcx - 0.5f * pw, 0.0f);
    float y1 = pcy - 0.5f * ph;
    float x2 = pcx + 0.5f * pw;
    float y2 = pcy + 0.5f * ph;
    x1 = fmaxf(x1, 0.0f);
    y1 = fmaxf(y1, 0.0f);
    x2 = fminf(x2, WH);
    y2 = fminf(y2, WH);
    bx1 = x1; by1 = y1; bx2 = x2; by2 = y2;
    barea = (bx2 - bx1) * (by2 - by1);
    active = true;
  }

  // ---- pre-init all outputs to "invalid" (harness re-poisons d_out) ----
  float* out_s = out;
  float* out_c = out + (size_t)C * MAXDET;
  float* out_b = out + (size_t)2 * C * MAXDET;
  if (tid < MAXDET) {
    out_s[c * MAXDET + tid] = 0.0f;
    out_c[c * MAXDET + tid] = -1.0f;
    float4 z; z.x = z.y = z.z = z.w = 0.0f;
    ((float4*)out_b)[c * MAXDET + tid] = z;
  }
  __syncthreads();

  // ---- phase 6: greedy NMS ----
  const int wid = tid >> 6, lane = tid & 63;
  for (int k = 0; k < MAXDET; k++) {
    unsigned long long v = active ? key : 0ULL;
    #pragma unroll
    for (int off = 32; off > 0; off >>= 1) {
      unsigned long long o = __shfl_down(v, (unsigned)off);
      if (o > v) v = o;
    }
    if (lane == 0) warr[wid] = v;
    __syncthreads();
    if (tid == 0) {
      unsigned long long b = 0ULL;
      #pragma unroll
      for (int wi = 0; wi < TPB / 64; wi++) if (warr[wi] > b) b = warr[wi];
      sbest = b;
    }
    __syncthreads();
    unsigned long long best = sbest;
    if (best == 0ULL) break;           // uniform: no candidates remain
    if (active && key == best) {
      spick[0] = bx1; spick[1] = by1; spick[2] = bx2; spick[3] = by2; spick[4] = barea;
      out_s[c * MAXDET + k] = bscore;
      out_c[c * MAXDET + k] = (float)c;
      float4 bb; bb.x = bx1; bb.y = by1; bb.z = bx2; bb.w = by2;
      ((float4*)out_b)[c * MAXDET + k] = bb;
      active = false;
    }
    __syncthreads();
    if (active) {
      float px1 = spick[0], py1 = spick[1], px2 = spick[2], py2 = spick[3], pa = spick[4];
      float ix1 = fmaxf(px1, bx1);
      float iy1 = fmaxf(py1, by1);
      float ix2 = fminf(px2, bx2);
      float iy2 = fminf(py2, by2);
      float inter = fmaxf(ix2 - ix1, 0.0f) * fmaxf(iy2 - iy1, 0.0f);
      float denom = ((pa + barea) - inter) + 1e-8f;   // areas[i]+areas-inter+1e-8
      float iou = inter / denom;
      if (iou > 0.5f) active = false;
    }
  }
}

extern "C" void kernel_launch(void* const* d_in, const int* in_sizes, int n_in,
                              void* d_out, int out_size, void* d_ws, size_t ws_size,
                              hipStream_t stream) {
  const float* cls     = (const float*)d_in[1];   // [1, C, N]
  const float* regp    = (const float*)d_in[2];   // [1, 4, N]
  const float* anchors = (const float*)d_in[3];   // [N, 4]
  const int N = in_sizes[3] / 4;
  const int C = in_sizes[1] / N;
  const int hw = (int)lround(sqrt((double)(in_sizes[0] / 3)));   // H == W
  retina_post_kernel<<<C, TPB, 0, stream>>>(cls, regp, anchors, (float*)d_out,
                                            N, C, (float)hw);
}